// Round 5
// baseline (441.636 us; speedup 1.0000x reference)
//
#include <hip/hip_runtime.h>

// EUNN: 256 layers; each layer = rotation on even pairs (2i,2i+1), then
// rotation on odd pairs (2i+1,2i+2 mod H).
// Pair math: y0 = e^{i*phi} (ct*u - st*v); y1 = st*u + ct*v.

#define H_DIM 1024
#define C2 256
#define RPW 2   // batch rows per wave

// coef layout: [c][j][lane] as float4 (ct, st, cp, sp); j in [0,16):
//   j=0..7  : phase A pair (local 2j, 2j+1) of lane
//   j=8..14 : phase B internal pair (local 2j-8+1, 2j-8+2)
//   j=15    : phase B boundary pair (lane elem15, next lane's elem0)
// flat float4 index: (c*16 + j)*64 + lane,  16 KB per layer, 4 MB total.

__global__ __launch_bounds__(256) void eunn_coef_kernel(
    const float* __restrict__ phi0, const float* __restrict__ theta0,
    const float* __restrict__ phi1, const float* __restrict__ theta1,
    float4* __restrict__ coef) {
    int t = blockIdx.x * 256 + threadIdx.x;   // [0, 262144)
    int c = t & 255;                          // layer in low bits -> coalesced reads
    int ip = t >> 8;                          // [0,1024)
    int i = ip >> 1;                          // pair index [0,512)
    int p = ip & 1;                           // phase
    const float* phi   = p ? phi1   : phi0;
    const float* theta = p ? theta1 : theta0;
    float ph = phi[i * C2 + c];
    float th = theta[i * C2 + c];
    float sp, cp, st, ct;
    __sincosf(ph, &sp, &cp);
    __sincosf(th, &st, &ct);
    int j = (i & 7) + 8 * p;                  // j slot: A pairs 0..7, B pairs 8..15
    int l = i >> 3;
    coef[((c * 16) + j) * 64 + l] = make_float4(ct, st, cp, sp);
}

__device__ __forceinline__ void rot_pair(const float4 q,
                                         float& ur, float& ui,
                                         float& wr, float& wi) {
    // q = (ct, st, cp, sp)
    float ar = fmaf(-q.y, wr, q.x * ur);   // ct*u - st*v (real part)
    float ai = fmaf(-q.y, wi, q.x * ui);
    float br = fmaf( q.x, wr, q.y * ur);   // st*u + ct*v
    float bi = fmaf( q.x, wi, q.y * ui);
    ur = fmaf(-q.w, ai, q.z * ar);         // e^{i phi} * a
    ui = fmaf( q.w, ar, q.z * ai);
    wr = br;
    wi = bi;
}

// NOTE (R3 post-mortem): no min-waves arg > 2 here. (256,4) capped VGPRs at
// 128 and the compiler squeezed state through extra moves -> 526us.
__global__ __launch_bounds__(256, 2) void eunn_main_kernel(
    const float* __restrict__ x,
    const float4* __restrict__ coef,
    float* __restrict__ out) {
    // double-buffered per-layer coefficient staging: 2 x 16 KB
    __shared__ float lds[8192];

    const int t = threadIdx.x;
    const int lane = t & 63;
    const int wave = t >> 6;
    const int row0 = (blockIdx.x * 4 + wave) * RPW;

    // lane owns complex elements [16*lane, 16*lane+16) of each of its RPW rows
    float vr[RPW][16], vi[RPW][16];

#pragma unroll
    for (int r = 0; r < RPW; ++r) {
        const float4* src = (const float4*)(x + (size_t)(row0 + r) * (H_DIM * 2)) + lane * 8;
#pragma unroll
        for (int m = 0; m < 8; ++m) {
            float4 f = src[m];
            vr[r][2 * m]     = f.x; vi[r][2 * m]     = f.y;
            vr[r][2 * m + 1] = f.z; vi[r][2 * m + 1] = f.w;
        }
    }

    // stage layer 0 into slot 0: 16 KB via 4x global_load_lds(width=16)/thread
    {
        const char* g = (const char*)coef + (size_t)t * 16;
        float* l = lds + t * 4;
#pragma unroll
        for (int k = 0; k < 4; ++k) {
            __builtin_amdgcn_global_load_lds(
                (const __attribute__((address_space(1))) void*)(g + k * 4096),
                (__attribute__((address_space(3))) void*)(l + k * 1024), 16, 0, 0);
        }
    }
    __syncthreads();

#pragma unroll 1
    for (int c = 0; c < C2; ++c) {
        // prefetch layer c+1 into the other slot (no wait here; the barrier
        // at the end of this iteration drains vmcnt before anyone reads it)
        if (c + 1 < C2) {
            const char* g = (const char*)coef + (size_t)(c + 1) * 16384 + (size_t)t * 16;
            float* l = lds + ((c + 1) & 1) * 4096 + t * 4;
#pragma unroll
            for (int k = 0; k < 4; ++k) {
                __builtin_amdgcn_global_load_lds(
                    (const __attribute__((address_space(1))) void*)(g + k * 4096),
                    (__attribute__((address_space(3))) void*)(l + k * 1024), 16, 0, 0);
            }
        }

        const float4* lq = (const float4*)(lds + (c & 1) * 4096) + lane;

        // boundary coef for phase B, read up front; prev-lane copy via shuffle
        float4 qq = lq[15 * 64];
        float qpx = __shfl(qq.x, (lane + 63) & 63);   // prev lane's ct'
        float qpy = __shfl(qq.y, (lane + 63) & 63);   // prev lane's st'

        // --- phase A, boundary-adjacent pairs first (j=0 and j=7) so the
        // cross-lane shuffles can issue early and hide under the FMA work.
        {
            float4 q0 = lq[0 * 64];
            float4 q7 = lq[7 * 64];
#pragma unroll
            for (int r = 0; r < RPW; ++r) {
                rot_pair(q0, vr[r][0],  vi[r][0],  vr[r][1],  vi[r][1]);
                rot_pair(q7, vr[r][14], vi[r][14], vr[r][15], vi[r][15]);
            }
        }
        // post-phase-A elem0 / elem15 feed the phase-B boundary pair
        float nbr[RPW], nbi[RPW], pbr[RPW], pbi[RPW];
#pragma unroll
        for (int r = 0; r < RPW; ++r) {
            nbr[r] = __shfl(vr[r][0],  (lane + 1)  & 63);   // next lane's elem0
            nbi[r] = __shfl(vi[r][0],  (lane + 1)  & 63);
            pbr[r] = __shfl(vr[r][15], (lane + 63) & 63);   // prev lane's elem15
            pbi[r] = __shfl(vi[r][15], (lane + 63) & 63);
        }

        // --- phase A remaining pairs j=1..6
#pragma unroll
        for (int j = 1; j < 7; ++j) {
            float4 q = lq[j * 64];
#pragma unroll
            for (int r = 0; r < RPW; ++r) {
                rot_pair(q, vr[r][2 * j],     vi[r][2 * j],
                            vr[r][2 * j + 1], vi[r][2 * j + 1]);
            }
        }

        // --- phase B internal pairs (local 2j+1, 2j+2), j=0..6
#pragma unroll
        for (int j = 0; j < 7; ++j) {
            float4 q = lq[(8 + j) * 64];
#pragma unroll
            for (int r = 0; r < RPW; ++r) {
                rot_pair(q, vr[r][2 * j + 1], vi[r][2 * j + 1],
                            vr[r][2 * j + 2], vi[r][2 * j + 2]);
            }
        }

        // --- phase B boundary pair (my elem15, next lane's elem0): both
        // sides computed locally from the pre-issued shuffles.
#pragma unroll
        for (int r = 0; r < RPW; ++r) {
            // new elem15 = e^{i phi}(ct*e15 - st*next_e0)
            float ar = fmaf(-qq.y, nbr[r], qq.x * vr[r][15]);
            float ai = fmaf(-qq.y, nbi[r], qq.x * vi[r][15]);
            vr[r][15] = fmaf(-qq.w, ai, qq.z * ar);
            vi[r][15] = fmaf( qq.w, ar, qq.z * ai);
            // new elem0 = st'*prev_e15 + ct'*e0  (lane-1's pair, second row)
            float b0r = fmaf(qpx, vr[r][0], qpy * pbr[r]);
            float b0i = fmaf(qpx, vi[r][0], qpy * pbi[r]);
            vr[r][0] = b0r; vi[r][0] = b0i;
        }

        // one barrier per layer: (a) all waves done reading slot c&1, so the
        // next iteration may overwrite it; (b) syncthreads' vmcnt drain makes
        // the c+1 prefetch visible before anyone reads it.
        __syncthreads();
    }

#pragma unroll
    for (int r = 0; r < RPW; ++r) {
        float4* dst = (float4*)(out + (size_t)(row0 + r) * (H_DIM * 2)) + lane * 8;
#pragma unroll
        for (int m = 0; m < 8; ++m) {
            dst[m] = make_float4(vr[r][2 * m],     vi[r][2 * m],
                                 vr[r][2 * m + 1], vi[r][2 * m + 1]);
        }
    }
}

extern "C" void kernel_launch(void* const* d_in, const int* in_sizes, int n_in,
                              void* d_out, int out_size, void* d_ws, size_t ws_size,
                              hipStream_t stream) {
    const float* x      = (const float*)d_in[0];
    const float* phi0   = (const float*)d_in[1];
    const float* theta0 = (const float*)d_in[2];
    const float* phi1   = (const float*)d_in[3];
    const float* theta1 = (const float*)d_in[4];
    float* out = (float*)d_out;
    float4* coef = (float4*)d_ws;   // 256 layers * 16 * 64 float4 = 4 MB

    // coefficients: 256 layers * 2 phases * 512 pairs = 262144 threads
    hipLaunchKernelGGL(eunn_coef_kernel, dim3(1024), dim3(256), 0, stream,
                       phi0, theta0, phi1, theta1, coef);

    // main: 4096 rows / (4 waves/block * RPW rows/wave) = 512 blocks
    hipLaunchKernelGGL(eunn_main_kernel, dim3(512), dim3(256), 0, stream,
                       x, coef, out);
}